// Round 3
// baseline (37.525 us; speedup 1.0000x reference)
//
#include <hip/hip_runtime.h>
#include <math.h>

#define EPSF 1e-9f
#define FOUR_PI 12.566370614359172f
#define YIM (-(FOUR_PI * 1e-9f))   // constant imag part of k^2 argument

__device__ __forceinline__ float frcp(float x)  { return __builtin_amdgcn_rcpf(x); }
__device__ __forceinline__ float frsq(float x)  { return __builtin_amdgcn_rsqf(x); }
__device__ __forceinline__ float fsq(float x)   { return __builtin_amdgcn_sqrtf(x); }

// principal sqrt of (x + i*YIM), YIM < 0 constant.
// Large component direct, small as Y/(2*large); one rsq serves both.
__device__ __forceinline__ void csqrt_negim(float x, float& u, float& v) {
    float r   = fsq(fmaf(x, x, YIM * YIM));
    float h   = 0.5f * (r + fabsf(x));
    float irs = frsq(h);            // 1/sqrt(h)
    float w   = h * irs;            // sqrt(h)   (large component, > 0)
    float o   = (0.5f * YIM) * irs; // Y/(2w)    (small component, <= 0)
    if (x >= 0.0f) { u = w;  v = o;  }
    else           { u = -o; v = -w; }
}

__global__ __launch_bounds__(256) void abeles_kernel(
    const float* __restrict__ qarr,   // B*Q
    const float* __restrict__ thick,  // B*L
    const float* __restrict__ rough,  // B*L
    const float* __restrict__ sld,    // B*(L+1)
    float* __restrict__ out,          // B*Q
    int Q, int L)
{
    const int b  = blockIdx.y;
    const int tx = threadIdx.x;

    __shared__ float s_xp[65];   // 4*pi*1e-6*(sld[j]-sld[0])
    __shared__ float s_t2[64];   // 2*thickness
    __shared__ float s_m2[64];   // -2*roughness^2

    if (tx < L + 1) {
        float s0 = sld[b * (L + 1)];
        s_xp[tx] = (FOUR_PI * 1e-6f) * (sld[b * (L + 1) + tx] - s0);
    } else if (tx < 2 * L + 1) {
        int j = tx - (L + 1);
        s_t2[j] = 2.0f * thick[b * L + j];
    } else if (tx < 3 * L + 1) {
        int j = tx - (2 * L + 1);
        float rr = rough[b * L + j];
        s_m2[j] = -2.0f * rr * rr;
    }

    const int iq = blockIdx.x * blockDim.x + tx;
    float qh = (iq < Q) ? 0.5f * qarr[b * Q + iq] : 0.05f;
    float q2 = qh * qh;

    __syncthreads();

    // k at the substrate (layer L); R = N/D with N=0, D=1
    float u2, v2;
    csqrt_negim(q2 - s_xp[L], u2, v2);
    float Nr = 0.0f, Ni = 0.0f, Dr = 1.0f, Di = 0.0f;

    #pragma unroll 8
    for (int j = L - 1; j >= 0; --j) {
        // k of layer j
        float u1, v1;
        csqrt_negim(q2 - s_xp[j], u1, v1);

        // fresnel (k1-k2)/(k1+k2+EPS)
        float nr = u1 - u2, ni = v1 - v2;
        float er = u1 + u2 + EPSF, ei = v1 + v2;
        float inv = frcp(fmaf(er, er, ei * ei));
        float rr = (nr * er + ni * ei) * inv;
        float ri = (ni * er - nr * ei) * inv;

        // roughness exp(m2 * k1*k2), m2 = -2*sigma^2
        float kkr = u1 * u2 - v1 * v2;
        float kki = u1 * v2 + v1 * u2;
        float m2 = s_m2[j];
        float ew = __expf(m2 * kkr);
        float sw, cw;
        __sincosf(m2 * kki, &sw, &cw);
        float fr = ew * cw, fi = ew * sw;
        float tr = rr * fr - ri * fi;
        ri = fmaf(rr, fi, ri * fr);
        rr = tr;

        // division-free Mobius: N' = p*(r*D + N), D' = D + r*N
        float tnr = fmaf(rr, Dr, fmaf(-ri, Di, Nr));
        float tni = fmaf(rr, Di, fmaf( ri, Dr, Ni));
        float tdr = fmaf(rr, Nr, fmaf(-ri, Ni, Dr));
        float tdi = fmaf(rr, Ni, fmaf( ri, Nr, Di));

        // phase p = e^{-2 i t k1} = e^{t2*v1} (cos(t2*u1) - i sin(t2*u1))
        float t2v = s_t2[j];
        float pm = __expf(t2v * v1);
        float sp, cp;
        __sincosf(t2v * u1, &sp, &cp);
        float pr = pm * cp, pi = -pm * sp;

        Nr = tnr * pr - tni * pi;
        Ni = fmaf(tnr, pi, tni * pr);
        Dr = tdr; Di = tdi;

        u2 = u1; v2 = v1;

        // renorm insurance every 16 layers (ratio-preserving)
        if ((j & 15) == 0) {
            float m = fabsf(Dr) + fabsf(Di);
            float s = 1.0f;
            if (m > 1e18f) s = 1e-18f;
            else if (m < 1e-18f) s = 1e18f;
            Nr *= s; Ni *= s; Dr *= s; Di *= s;
        }
    }

    // |N/D|^2
    float inv = frcp(fmaf(Dr, Dr, Di * Di));
    float qr = (Nr * Dr + Ni * Di) * inv;
    float qi = (Ni * Dr - Nr * Di) * inv;
    if (iq < Q) out[b * Q + iq] = fmaf(qr, qr, qi * qi);
}

extern "C" void kernel_launch(void* const* d_in, const int* in_sizes, int n_in,
                              void* d_out, int out_size, void* d_ws, size_t ws_size,
                              hipStream_t stream) {
    const float* q     = (const float*)d_in[0];
    const float* thick = (const float*)d_in[1];
    const float* rough = (const float*)d_in[2];
    const float* sld   = (const float*)d_in[3];
    float* out = (float*)d_out;

    int B = in_sizes[3] - in_sizes[1];   // B*(L+1) - B*L
    int L = in_sizes[1] / B;
    int Q = in_sizes[0] / B;

    dim3 block(256);
    dim3 grid((Q + 255) / 256, B);
    abeles_kernel<<<grid, block, 0, stream>>>(q, thick, rough, sld, out, Q, L);
}